// Round 5
// baseline (1192.927 us; speedup 1.0000x reference)
//
#include <hip/hip_runtime.h>
#include <hip/hip_fp16.h>
#include <stdint.h>

typedef int v4i __attribute__((ext_vector_type(4)));

#define GLOAD_LDS16(g, l) __builtin_amdgcn_global_load_lds(                  \
    (const __attribute__((address_space(1))) void*)(g),                      \
    (__attribute__((address_space(3))) void*)(l), 16, 0, 0)

// workspace layout (bytes)
#define XQ_OFF 0u
#define XS_OFF 33554432u              // M*K int8
#define W8_OFF 33570816u              // + M*2 fp16 scales

// ---------------------------------------------------------------------------
// Self-classification of input delivery: x widened fp16->f32 has low 13
// mantissa bits zero; w widened int8->int32 has every word in [-128,127].
// ---------------------------------------------------------------------------
__device__ inline bool x_is_f32(const void* xin) {
  const uint32_t* xw = (const uint32_t*)xin;
  bool ok = true;
  #pragma unroll
  for (int i = 0; i < 16; ++i) ok &= ((xw[i] & 0x1FFFu) == 0u);
  return ok;
}
__device__ inline bool w_is_i32(const void* win) {
  const int* wi = (const int*)win;
  bool ok = true;
  #pragma unroll
  for (int i = 0; i < 16; ++i) ok &= (wi[i] >= -128 && wi[i] <= 127);
  return ok;
}

// ---------------------------------------------------------------------------
// Repack w into contiguous int8 [N*K] (narrow int32 or straight copy).
// ---------------------------------------------------------------------------
__global__ __launch_bounds__(256) void repack_w(
    const void* __restrict__ win, int8_t* __restrict__ w8, int total)
{
  const bool as32 = w_is_i32(win);
  const int tid  = blockIdx.x * 256 + threadIdx.x;
  const int nthr = gridDim.x * 256;
  if (as32) {
    const int4* w4 = (const int4*)win;
    uint32_t* dst = (uint32_t*)w8;
    const int n4 = total >> 2;
    for (int i = tid; i < n4; i += nthr) {
      int4 v = w4[i];
      dst[i] = (uint32_t)(v.x & 255) | ((uint32_t)(v.y & 255) << 8) |
               ((uint32_t)(v.z & 255) << 16) | ((uint32_t)(v.w & 255) << 24);
    }
  } else {
    const uint4* src = (const uint4*)win;
    uint4* dst = (uint4*)w8;
    const int n16 = total >> 4;
    for (int i = tid; i < n16; i += nthr) dst[i] = src[i];
  }
}

// ---------------------------------------------------------------------------
// Per-token dynamic symmetric int8 quantization, one block per row.
// Fast path (f32 input, K==4096): row cached in registers, single HBM pass.
// ---------------------------------------------------------------------------
__global__ __launch_bounds__(256) void quant_rows(
    const void* __restrict__ xin, int8_t* __restrict__ xq,
    __half* __restrict__ xs, int K)
{
  const bool xf32 = x_is_f32(xin);
  const int row  = blockIdx.x;
  const int tid  = threadIdx.x;
  const int lane = tid & 63;
  const int wv   = tid >> 6;
  const size_t base = (size_t)row * (size_t)K;
  __shared__ float wmax[4];

  if (xf32 && K == 4096) {
    const float4* x4 = (const float4*)((const float*)xin + base);
    float4 v[4];
    #pragma unroll
    for (int i = 0; i < 4; ++i) v[i] = x4[i * 256 + tid];
    float mx = 0.0f;
    #pragma unroll
    for (int i = 0; i < 4; ++i)
      mx = fmaxf(mx, fmaxf(fmaxf(fabsf(v[i].x), fabsf(v[i].y)),
                           fmaxf(fabsf(v[i].z), fabsf(v[i].w))));
    #pragma unroll
    for (int off = 32; off; off >>= 1) mx = fmaxf(mx, __shfl_xor(mx, off, 64));
    if (lane == 0) wmax[wv] = mx;
    __syncthreads();
    const float scale =
        fmaxf(fmaxf(wmax[0], wmax[1]), fmaxf(wmax[2], wmax[3])) / 127.0f;
    if (tid == 0) xs[row] = __float2half(scale);
    uint32_t* q = (uint32_t*)(xq + base);
    #pragma unroll
    for (int i = 0; i < 4; ++i) {
      float f[4] = {v[i].x, v[i].y, v[i].z, v[i].w};
      uint32_t p = 0;
      #pragma unroll
      for (int j = 0; j < 4; ++j) {
        float r = fminf(127.0f, fmaxf(-128.0f, rintf(f[j] / scale)));
        p |= ((uint32_t)((int)r & 255)) << (8 * j);
      }
      q[i * 256 + tid] = p;
    }
    return;
  }

  // generic two-pass fallback
  float mx = 0.0f;
  if (xf32) {
    const float* x = (const float*)xin + base;
    for (int k = tid * 4; k < K; k += 256 * 4) {
      float4 v = *(const float4*)(x + k);
      mx = fmaxf(mx, fmaxf(fmaxf(fabsf(v.x), fabsf(v.y)),
                           fmaxf(fabsf(v.z), fabsf(v.w))));
    }
  } else {
    const __half* x = (const __half*)xin + base;
    for (int k = tid * 8; k < K; k += 256 * 8) {
      uint4 u = *(const uint4*)(x + k);
      const __half* hp = (const __half*)&u;
      #pragma unroll
      for (int j = 0; j < 8; ++j) mx = fmaxf(mx, fabsf(__half2float(hp[j])));
    }
  }
  #pragma unroll
  for (int off = 32; off; off >>= 1) mx = fmaxf(mx, __shfl_xor(mx, off, 64));
  if (lane == 0) wmax[wv] = mx;
  __syncthreads();
  const float scale =
      fmaxf(fmaxf(wmax[0], wmax[1]), fmaxf(wmax[2], wmax[3])) / 127.0f;
  if (tid == 0) xs[row] = __float2half(scale);

  for (int k = tid * 8; k < K; k += 256 * 8) {
    float f[8];
    if (xf32) {
      const float* x = (const float*)xin + base;
      float4 a = *(const float4*)(x + k);
      float4 b = *(const float4*)(x + k + 4);
      f[0]=a.x; f[1]=a.y; f[2]=a.z; f[3]=a.w; f[4]=b.x; f[5]=b.y; f[6]=b.z; f[7]=b.w;
    } else {
      const __half* x = (const __half*)xin + base;
      uint4 u = *(const uint4*)(x + k);
      const __half* hp = (const __half*)&u;
      #pragma unroll
      for (int j = 0; j < 8; ++j) f[j] = __half2float(hp[j]);
    }
    uint32_t p0 = 0, p1 = 0;
    #pragma unroll
    for (int j = 0; j < 4; ++j) {
      float r = fminf(127.0f, fmaxf(-128.0f, rintf(f[j] / scale)));
      p0 |= ((uint32_t)((int)r & 255)) << (8 * j);
    }
    #pragma unroll
    for (int j = 0; j < 4; ++j) {
      float r = fminf(127.0f, fmaxf(-128.0f, rintf(f[4 + j] / scale)));
      p1 |= ((uint32_t)((int)r & 255)) << (8 * j);
    }
    uint2 st; st.x = p0; st.y = p1;
    *(uint2*)(xq + base + k) = st;
  }
}

// ---------------------------------------------------------------------------
// int8 GEMM, 256x256 tile, BK=64, 8 waves (2Mx4N), DOUBLE-buffered LDS (64KiB
// -> 2 blocks/CU, 4 waves/SIMD from independent blocks), round-3 tile body
// (interleaved stage/read/MFMA, 1 barrier per K-tile, drain vmcnt(0)).
// Inter-block skew hides the drain. Requires K%64==0, M,N%256==0, K/64>=2.
// ---------------------------------------------------------------------------
__global__ __launch_bounds__(512, 4) void gemm_w8a8(
    const int8_t* __restrict__ xq, const int8_t* __restrict__ wq,
    const __half* __restrict__ xs, const float* __restrict__ wscale,
    const float* __restrict__ mos, float* __restrict__ out,
    int M, int N, int K)
{
  __shared__ int8_t sA[2][256 * 64];   // 32 KiB
  __shared__ int8_t sB[2][256 * 64];   // 32 KiB

  const int tid  = threadIdx.x;
  const int lane = tid & 63;
  const int w    = tid >> 6;
  const int wr   = w >> 2;        // 0..1 -> 128 rows of C
  const int wc   = w & 3;         // 0..3 -> 64 cols of C
  const int lr   = lane & 15;
  const int lk   = lane >> 4;

  // XCD-aware swizzle (bijective: gridDim.x % 8 == 0 for our shapes)
  int L = blockIdx.x;
  const int nwg = gridDim.x;
  if ((nwg & 7) == 0) L = (L & 7) * (nwg >> 3) + (L >> 3);
  const int ntn = N >> 8;
  const int bn = (L % ntn) << 8;
  const int bm = (L / ntn) << 8;

  v4i acc[8][4];
  #pragma unroll
  for (int i = 0; i < 8; ++i)
    #pragma unroll
    for (int j = 0; j < 4; ++j) {
      v4i z = {0, 0, 0, 0};
      acc[i][j] = z;
    }

  // stage 256x64B tile; LDS pos (r,p) holds global chunk p ^ ((r>>1)&3)
  auto stageA = [&](int kt, int buf) {
    const int k0 = kt << 6;
    #pragma unroll
    for (int i = 0; i < 2; ++i) {
      const int li = i * 512 + tid;
      const int r  = li >> 2;
      const int p  = li & 3;
      const int sc = p ^ ((r >> 1) & 3);
      GLOAD_LDS16(xq + (size_t)(bm + r) * K + k0 + (sc << 4),
                  &sA[buf][(i * 512 + (w << 6)) << 4]);
    }
  };
  auto stageB = [&](int kt, int buf) {
    const int k0 = kt << 6;
    #pragma unroll
    for (int i = 0; i < 2; ++i) {
      const int li = i * 512 + tid;
      const int r  = li >> 2;
      const int p  = li & 3;
      const int sc = p ^ ((r >> 1) & 3);
      GLOAD_LDS16(wq + (size_t)(bn + r) * K + k0 + (sc << 4),
                  &sB[buf][(i * 512 + (w << 6)) << 4]);
    }
  };

  // swizzled ds_read byte offsets; invariant under row += 16 steps
  const int rowA0 = (wr << 7) + lr;
  const int aoff  = rowA0 * 64 + ((lk ^ ((rowA0 >> 1) & 3)) << 4);
  const int rowB0 = (wc << 6) + lr;
  const int boff  = rowB0 * 64 + ((lk ^ ((rowB0 >> 1) & 3)) << 4);

  const int nt = K >> 6;

  // prologue: stage tile 0, drain, sync
  stageA(0, 0); stageB(0, 0);
  asm volatile("s_waitcnt vmcnt(0)" ::: "memory");
  __builtin_amdgcn_s_barrier();

  #pragma unroll 1
  for (int t = 0; t < nt; ++t) {
    const int buf = t & 1;
    const int8_t* Ab = sA[buf];
    const int8_t* Bb = sB[buf];
    const bool do_stage = (t + 1 < nt);

    if (do_stage) stageA(t + 1, buf ^ 1);

    v4i af[4], bf[4];
    #pragma unroll
    for (int ni = 0; ni < 4; ++ni) bf[ni] = *(const v4i*)(Bb + boff + ni * 1024);
    #pragma unroll
    for (int mi = 0; mi < 4; ++mi) af[mi] = *(const v4i*)(Ab + aoff + mi * 1024);
    __builtin_amdgcn_s_setprio(1);
    #pragma unroll
    for (int mi = 0; mi < 4; ++mi)
      #pragma unroll
      for (int ni = 0; ni < 4; ++ni)
        acc[mi][ni] = __builtin_amdgcn_mfma_i32_16x16x64_i8(
            af[mi], bf[ni], acc[mi][ni], 0, 0, 0);
    __builtin_amdgcn_s_setprio(0);

    if (do_stage) stageB(t + 1, buf ^ 1);

    #pragma unroll
    for (int mi = 0; mi < 4; ++mi)
      af[mi] = *(const v4i*)(Ab + aoff + 4096 + mi * 1024);
    __builtin_amdgcn_s_setprio(1);
    #pragma unroll
    for (int mi = 0; mi < 4; ++mi)
      #pragma unroll
      for (int ni = 0; ni < 4; ++ni)
        acc[mi + 4][ni] = __builtin_amdgcn_mfma_i32_16x16x64_i8(
            af[mi], bf[ni], acc[mi + 4][ni], 0, 0, 0);
    __builtin_amdgcn_s_setprio(0);

    // drain staged loads (t+1) + this tile's ds_reads (WAR for next stage)
    asm volatile("s_waitcnt vmcnt(0) lgkmcnt(0)" ::: "memory");
    __builtin_amdgcn_s_barrier();
  }

  // epilogue: out = (float(half(acc*s_out)) * wscale[n]) * float(half_scale[m])
  const float s_out = mos[0];
  #pragma unroll
  for (int ni = 0; ni < 4; ++ni) {
    const int n_g = bn + (wc << 6) + ni * 16 + lr;
    const float wsc = wscale[n_g];
    #pragma unroll
    for (int mi = 0; mi < 8; ++mi) {
      #pragma unroll
      for (int j = 0; j < 4; ++j) {
        const int m_g = bm + (wr << 7) + mi * 16 + lk * 4 + j;
        const float y = __half2float(__float2half((float)acc[mi][ni][j] * s_out));
        out[(size_t)m_g * N + n_g] = (y * wsc) * __half2float(xs[m_g]);
      }
    }
  }
}

// ---------------------------------------------------------------------------
extern "C" void kernel_launch(void* const* d_in, const int* in_sizes, int n_in,
                              void* d_out, int out_size, void* d_ws, size_t ws_size,
                              hipStream_t stream) {
  const void*  x      = d_in[0];
  const void*  win    = d_in[1];
  const float* wscale = (const float*)d_in[2];
  const float* mos    = (const float*)d_in[3];
  float*       out    = (float*)d_out;

  const int N = in_sizes[2];            // 4096
  const int K = in_sizes[1] / N;        // 4096
  const int M = in_sizes[0] / K;        // 8192

  int8_t* xq = (int8_t*)d_ws + XQ_OFF;
  __half* xs = (__half*)((char*)d_ws + XS_OFF);
  int8_t* w8 = (int8_t*)d_ws + W8_OFF;

  repack_w<<<2048, 256, 0, stream>>>(win, w8, N * K);
  quant_rows<<<M, 256, 0, stream>>>(x, xq, xs, K);

  gemm_w8a8<<<dim3((M >> 8) * (N >> 8)), 512, 0, stream>>>(
      xq, w8, xs, wscale, mos, out, M, N, K);
}

// Round 6
// 202.384 us; speedup vs baseline: 5.8944x; 5.8944x over previous
//
#include <hip/hip_runtime.h>
#include <hip/hip_fp16.h>
#include <stdint.h>

typedef int v4i __attribute__((ext_vector_type(4)));

#define GLOAD_LDS16(g, l) __builtin_amdgcn_global_load_lds(                  \
    (const __attribute__((address_space(1))) void*)(g),                      \
    (__attribute__((address_space(3))) void*)(l), 16, 0, 0)

// workspace layout (bytes)
#define XQ_OFF 0u
#define XS_OFF 33554432u              // M*K int8
#define W8_OFF 33570816u              // + M*2 fp16 scales

// ---------------------------------------------------------------------------
// Self-classification of input delivery: x widened fp16->f32 has low 13
// mantissa bits zero; w widened int8->int32 has every word in [-128,127].
// ---------------------------------------------------------------------------
__device__ inline bool x_is_f32(const void* xin) {
  const uint32_t* xw = (const uint32_t*)xin;
  bool ok = true;
  #pragma unroll
  for (int i = 0; i < 16; ++i) ok &= ((xw[i] & 0x1FFFu) == 0u);
  return ok;
}
__device__ inline bool w_is_i32(const void* win) {
  const int* wi = (const int*)win;
  bool ok = true;
  #pragma unroll
  for (int i = 0; i < 16; ++i) ok &= (wi[i] >= -128 && wi[i] <= 127);
  return ok;
}

// ---------------------------------------------------------------------------
// Repack w into contiguous int8 [N*K] (narrow int32 or straight copy).
// ---------------------------------------------------------------------------
__global__ __launch_bounds__(256) void repack_w(
    const void* __restrict__ win, int8_t* __restrict__ w8, int total)
{
  const bool as32 = w_is_i32(win);
  const int tid  = blockIdx.x * 256 + threadIdx.x;
  const int nthr = gridDim.x * 256;
  if (as32) {
    const int4* w4 = (const int4*)win;
    uint32_t* dst = (uint32_t*)w8;
    const int n4 = total >> 2;
    for (int i = tid; i < n4; i += nthr) {
      int4 v = w4[i];
      dst[i] = (uint32_t)(v.x & 255) | ((uint32_t)(v.y & 255) << 8) |
               ((uint32_t)(v.z & 255) << 16) | ((uint32_t)(v.w & 255) << 24);
    }
  } else {
    const uint4* src = (const uint4*)win;
    uint4* dst = (uint4*)w8;
    const int n16 = total >> 4;
    for (int i = tid; i < n16; i += nthr) dst[i] = src[i];
  }
}

// ---------------------------------------------------------------------------
// Per-token dynamic symmetric int8 quantization, one block per row.
// Fast path (f32 input, K==4096): row cached in registers, single HBM pass.
// ---------------------------------------------------------------------------
__global__ __launch_bounds__(256) void quant_rows(
    const void* __restrict__ xin, int8_t* __restrict__ xq,
    __half* __restrict__ xs, int K)
{
  const bool xf32 = x_is_f32(xin);
  const int row  = blockIdx.x;
  const int tid  = threadIdx.x;
  const int lane = tid & 63;
  const int wv   = tid >> 6;
  const size_t base = (size_t)row * (size_t)K;
  __shared__ float wmax[4];

  if (xf32 && K == 4096) {
    const float4* x4 = (const float4*)((const float*)xin + base);
    float4 v[4];
    #pragma unroll
    for (int i = 0; i < 4; ++i) v[i] = x4[i * 256 + tid];
    float mx = 0.0f;
    #pragma unroll
    for (int i = 0; i < 4; ++i)
      mx = fmaxf(mx, fmaxf(fmaxf(fabsf(v[i].x), fabsf(v[i].y)),
                           fmaxf(fabsf(v[i].z), fabsf(v[i].w))));
    #pragma unroll
    for (int off = 32; off; off >>= 1) mx = fmaxf(mx, __shfl_xor(mx, off, 64));
    if (lane == 0) wmax[wv] = mx;
    __syncthreads();
    const float scale =
        fmaxf(fmaxf(wmax[0], wmax[1]), fmaxf(wmax[2], wmax[3])) / 127.0f;
    if (tid == 0) xs[row] = __float2half(scale);
    uint32_t* q = (uint32_t*)(xq + base);
    #pragma unroll
    for (int i = 0; i < 4; ++i) {
      float f[4] = {v[i].x, v[i].y, v[i].z, v[i].w};
      uint32_t p = 0;
      #pragma unroll
      for (int j = 0; j < 4; ++j) {
        float r = fminf(127.0f, fmaxf(-128.0f, rintf(f[j] / scale)));
        p |= ((uint32_t)((int)r & 255)) << (8 * j);
      }
      q[i * 256 + tid] = p;
    }
    return;
  }

  // generic two-pass fallback
  float mx = 0.0f;
  if (xf32) {
    const float* x = (const float*)xin + base;
    for (int k = tid * 4; k < K; k += 256 * 4) {
      float4 v = *(const float4*)(x + k);
      mx = fmaxf(mx, fmaxf(fmaxf(fabsf(v.x), fabsf(v.y)),
                           fmaxf(fabsf(v.z), fabsf(v.w))));
    }
  } else {
    const __half* x = (const __half*)xin + base;
    for (int k = tid * 8; k < K; k += 256 * 8) {
      uint4 u = *(const uint4*)(x + k);
      const __half* hp = (const __half*)&u;
      #pragma unroll
      for (int j = 0; j < 8; ++j) mx = fmaxf(mx, fabsf(__half2float(hp[j])));
    }
  }
  #pragma unroll
  for (int off = 32; off; off >>= 1) mx = fmaxf(mx, __shfl_xor(mx, off, 64));
  if (lane == 0) wmax[wv] = mx;
  __syncthreads();
  const float scale =
      fmaxf(fmaxf(wmax[0], wmax[1]), fmaxf(wmax[2], wmax[3])) / 127.0f;
  if (tid == 0) xs[row] = __float2half(scale);

  for (int k = tid * 8; k < K; k += 256 * 8) {
    float f[8];
    if (xf32) {
      const float* x = (const float*)xin + base;
      float4 a = *(const float4*)(x + k);
      float4 b = *(const float4*)(x + k + 4);
      f[0]=a.x; f[1]=a.y; f[2]=a.z; f[3]=a.w; f[4]=b.x; f[5]=b.y; f[6]=b.z; f[7]=b.w;
    } else {
      const __half* x = (const __half*)xin + base;
      uint4 u = *(const uint4*)(x + k);
      const __half* hp = (const __half*)&u;
      #pragma unroll
      for (int j = 0; j < 8; ++j) f[j] = __half2float(hp[j]);
    }
    uint32_t p0 = 0, p1 = 0;
    #pragma unroll
    for (int j = 0; j < 4; ++j) {
      float r = fminf(127.0f, fmaxf(-128.0f, rintf(f[j] / scale)));
      p0 |= ((uint32_t)((int)r & 255)) << (8 * j);
    }
    #pragma unroll
    for (int j = 0; j < 4; ++j) {
      float r = fminf(127.0f, fmaxf(-128.0f, rintf(f[4 + j] / scale)));
      p1 |= ((uint32_t)((int)r & 255)) << (8 * j);
    }
    uint2 st; st.x = p0; st.y = p1;
    *(uint2*)(xq + base + k) = st;
  }
}

// ---------------------------------------------------------------------------
// int8 GEMM, 256x256 tile, BK=64, 8 waves (2Mx4N), quad-buffered LDS (128KiB,
// 1 block/CU, 2 waves/SIMD), REGISTER double-buffered fragments: MFMA never
// waits on an in-iteration ds_read. Counted lgkmcnt(4)/lgkmcnt(0), counted
// vmcnt(4) (never drained mid-loop), raw s_barrier (1/tile), d=2 prefetch.
// Requires K % 64 == 0, K/64 >= 3, M,N % 256 == 0.
// ---------------------------------------------------------------------------
__global__ __launch_bounds__(512, 2) void gemm_w8a8(
    const int8_t* __restrict__ xq, const int8_t* __restrict__ wq,
    const __half* __restrict__ xs, const float* __restrict__ wscale,
    const float* __restrict__ mos, float* __restrict__ out,
    int M, int N, int K)
{
  __shared__ int8_t sA[4][256 * 64];   // 64 KiB
  __shared__ int8_t sB[4][256 * 64];   // 64 KiB

  const int tid  = threadIdx.x;
  const int lane = tid & 63;
  const int w    = tid >> 6;
  const int wr   = w >> 2;        // 0..1 -> 128 rows of C
  const int wc   = w & 3;         // 0..3 -> 64 cols of C
  const int lr   = lane & 15;
  const int lk   = lane >> 4;

  // XCD-aware swizzle (bijective: gridDim.x % 8 == 0 for our shapes)
  int L = blockIdx.x;
  const int nwg = gridDim.x;
  if ((nwg & 7) == 0) L = (L & 7) * (nwg >> 3) + (L >> 3);
  const int ntn = N >> 8;
  const int bn = (L % ntn) << 8;
  const int bm = (L / ntn) << 8;

  v4i acc[8][4];
  #pragma unroll
  for (int i = 0; i < 8; ++i)
    #pragma unroll
    for (int j = 0; j < 4; ++j) {
      v4i z = {0, 0, 0, 0};
      acc[i][j] = z;
    }

  // stage 256x64B tile; LDS pos (r,p) holds global chunk p ^ ((r>>1)&3)
  auto stageA = [&](int kt, int buf) {
    const int k0 = kt << 6;
    #pragma unroll
    for (int i = 0; i < 2; ++i) {
      const int li = i * 512 + tid;
      const int r  = li >> 2;
      const int p  = li & 3;
      const int sc = p ^ ((r >> 1) & 3);
      GLOAD_LDS16(xq + (size_t)(bm + r) * K + k0 + (sc << 4),
                  &sA[buf][(i * 512 + (w << 6)) << 4]);
    }
  };
  auto stageB = [&](int kt, int buf) {
    const int k0 = kt << 6;
    #pragma unroll
    for (int i = 0; i < 2; ++i) {
      const int li = i * 512 + tid;
      const int r  = li >> 2;
      const int p  = li & 3;
      const int sc = p ^ ((r >> 1) & 3);
      GLOAD_LDS16(wq + (size_t)(bn + r) * K + k0 + (sc << 4),
                  &sB[buf][(i * 512 + (w << 6)) << 4]);
    }
  };

  // swizzled ds_read byte offsets; invariant under row += 16 steps
  const int rowA0 = (wr << 7) + lr;
  const int aoff  = rowA0 * 64 + ((lk ^ ((rowA0 >> 1) & 3)) << 4);
  const int rowB0 = (wc << 6) + lr;
  const int boff  = rowB0 * 64 + ((lk ^ ((rowB0 >> 1) & 3)) << 4);

  const int nt = K >> 6;

  // prologue: 2 tiles in flight; wait for tile 0 only (tile 1 stays out)
  stageA(0, 0); stageB(0, 0);
  stageA(1, 1); stageB(1, 1);
  asm volatile("s_waitcnt vmcnt(4)" ::: "memory");
  __builtin_amdgcn_s_barrier();

  // preload tile-0 fragments: A half-0 + B
  v4i afc[4], afn[4], bfc[4];
  #pragma unroll
  for (int i = 0; i < 4; ++i) afc[i] = *(const v4i*)(&sA[0][aoff + i * 1024]);
  #pragma unroll
  for (int i = 0; i < 4; ++i) bfc[i] = *(const v4i*)(&sB[0][boff + i * 1024]);

  #pragma unroll 1
  for (int t = 0; t < nt; ++t) {
    const int buf = t & 3;
    const int8_t* Ab = sA[buf];

    // read A half-1 of tile t (consumed by MFMA h1 below)
    #pragma unroll
    for (int i = 0; i < 4; ++i)
      afn[i] = *(const v4i*)(Ab + aoff + 4096 + i * 1024);

    const bool do_stage = (t + 2 < nt);
    if (do_stage) stageA(t + 2, (t + 2) & 3);

    // last iter's 8 tail reads done; afn's 4 may remain outstanding
    asm volatile("s_waitcnt lgkmcnt(4)" ::: "memory");
    __builtin_amdgcn_s_setprio(1);
    #pragma unroll
    for (int mi = 0; mi < 4; ++mi)
      #pragma unroll
      for (int ni = 0; ni < 4; ++ni)
        acc[mi][ni] = __builtin_amdgcn_mfma_i32_16x16x64_i8(
            afc[mi], bfc[ni], acc[mi][ni], 0, 0, 0);
    __builtin_amdgcn_s_setprio(0);

    if (do_stage) stageB(t + 2, (t + 2) & 3);

    asm volatile("s_waitcnt lgkmcnt(0)" ::: "memory");
    __builtin_amdgcn_s_setprio(1);
    #pragma unroll
    for (int mi = 0; mi < 4; ++mi)
      #pragma unroll
      for (int ni = 0; ni < 4; ++ni)
        acc[mi + 4][ni] = __builtin_amdgcn_mfma_i32_16x16x64_i8(
            afn[mi], bfc[ni], acc[mi + 4][ni], 0, 0, 0);
    __builtin_amdgcn_s_setprio(0);

    if (t + 1 < nt) {
      // tile t+1's stage (issued last iter) must be resident for tail reads;
      // tile t+2's 4 loads (issued this iter) stay in flight.
      if (do_stage) {
        asm volatile("s_waitcnt vmcnt(4)" ::: "memory");
      } else {
        asm volatile("s_waitcnt vmcnt(0)" ::: "memory");
      }
      __builtin_amdgcn_s_barrier();
      const int nbuf = (t + 1) & 3;
      const int8_t* An = sA[nbuf];
      const int8_t* Bn = sB[nbuf];
      #pragma unroll
      for (int i = 0; i < 4; ++i) afc[i] = *(const v4i*)(An + aoff + i * 1024);
      #pragma unroll
      for (int i = 0; i < 4; ++i) bfc[i] = *(const v4i*)(Bn + boff + i * 1024);
    }
  }

  // epilogue: out = (float(half(acc*s_out)) * wscale[n]) * float(half_scale[m])
  const float s_out = mos[0];
  #pragma unroll
  for (int ni = 0; ni < 4; ++ni) {
    const int n_g = bn + (wc << 6) + ni * 16 + lr;
    const float wsc = wscale[n_g];
    #pragma unroll
    for (int mi = 0; mi < 8; ++mi) {
      #pragma unroll
      for (int j = 0; j < 4; ++j) {
        const int m_g = bm + (wr << 7) + mi * 16 + lk * 4 + j;
        const float y = __half2float(__float2half((float)acc[mi][ni][j] * s_out));
        out[(size_t)m_g * N + n_g] = (y * wsc) * __half2float(xs[m_g]);
      }
    }
  }
}

// ---------------------------------------------------------------------------
extern "C" void kernel_launch(void* const* d_in, const int* in_sizes, int n_in,
                              void* d_out, int out_size, void* d_ws, size_t ws_size,
                              hipStream_t stream) {
  const void*  x      = d_in[0];
  const void*  win    = d_in[1];
  const float* wscale = (const float*)d_in[2];
  const float* mos    = (const float*)d_in[3];
  float*       out    = (float*)d_out;

  const int N = in_sizes[2];            // 4096
  const int K = in_sizes[1] / N;        // 4096
  const int M = in_sizes[0] / K;        // 8192

  int8_t* xq = (int8_t*)d_ws + XQ_OFF;
  __half* xs = (__half*)((char*)d_ws + XS_OFF);
  int8_t* w8 = (int8_t*)d_ws + W8_OFF;

  repack_w<<<2048, 256, 0, stream>>>(win, w8, N * K);
  quant_rows<<<M, 256, 0, stream>>>(x, xq, xs, K);

  gemm_w8a8<<<dim3((M >> 8) * (N >> 8)), 512, 0, stream>>>(
      xq, w8, xs, wscale, mos, out, M, N, K);
}

// Round 7
// 189.997 us; speedup vs baseline: 6.2787x; 1.0652x over previous
//
#include <hip/hip_runtime.h>
#include <hip/hip_fp16.h>
#include <stdint.h>

typedef int v4i __attribute__((ext_vector_type(4)));

#define GLOAD_LDS16(g, l) __builtin_amdgcn_global_load_lds(                  \
    (const __attribute__((address_space(1))) void*)(g),                      \
    (__attribute__((address_space(3))) void*)(l), 16, 0, 0)

// workspace layout (bytes)
#define XQ_OFF 0u
#define XS_OFF 33554432u              // M*K int8
#define W8_OFF 33570816u              // + M*2 fp16 scales

// ---------------------------------------------------------------------------
// Self-classification of input delivery: x widened fp16->f32 has low 13
// mantissa bits zero; w widened int8->int32 has every word in [-128,127].
// ---------------------------------------------------------------------------
__device__ inline bool x_is_f32(const void* xin) {
  const uint32_t* xw = (const uint32_t*)xin;
  bool ok = true;
  #pragma unroll
  for (int i = 0; i < 16; ++i) ok &= ((xw[i] & 0x1FFFu) == 0u);
  return ok;
}
__device__ inline bool w_is_i32(const void* win) {
  const int* wi = (const int*)win;
  bool ok = true;
  #pragma unroll
  for (int i = 0; i < 16; ++i) ok &= (wi[i] >= -128 && wi[i] <= 127);
  return ok;
}

// ---------------------------------------------------------------------------
// Repack w into contiguous int8 [N*K] (narrow int32 or straight copy).
// ---------------------------------------------------------------------------
__global__ __launch_bounds__(256) void repack_w(
    const void* __restrict__ win, int8_t* __restrict__ w8, int total)
{
  const bool as32 = w_is_i32(win);
  const int tid  = blockIdx.x * 256 + threadIdx.x;
  const int nthr = gridDim.x * 256;
  if (as32) {
    const int4* w4 = (const int4*)win;
    uint32_t* dst = (uint32_t*)w8;
    const int n4 = total >> 2;
    for (int i = tid; i < n4; i += nthr) {
      int4 v = w4[i];
      dst[i] = (uint32_t)(v.x & 255) | ((uint32_t)(v.y & 255) << 8) |
               ((uint32_t)(v.z & 255) << 16) | ((uint32_t)(v.w & 255) << 24);
    }
  } else {
    const uint4* src = (const uint4*)win;
    uint4* dst = (uint4*)w8;
    const int n16 = total >> 4;
    for (int i = tid; i < n16; i += nthr) dst[i] = src[i];
  }
}

// ---------------------------------------------------------------------------
// Per-token dynamic symmetric int8 quantization, one block per row.
// Fast path (f32 input, K==4096): row cached in registers, single HBM pass.
// ---------------------------------------------------------------------------
__global__ __launch_bounds__(256) void quant_rows(
    const void* __restrict__ xin, int8_t* __restrict__ xq,
    __half* __restrict__ xs, int K)
{
  const bool xf32 = x_is_f32(xin);
  const int row  = blockIdx.x;
  const int tid  = threadIdx.x;
  const int lane = tid & 63;
  const int wv   = tid >> 6;
  const size_t base = (size_t)row * (size_t)K;
  __shared__ float wmax[4];

  if (xf32 && K == 4096) {
    const float4* x4 = (const float4*)((const float*)xin + base);
    float4 v[4];
    #pragma unroll
    for (int i = 0; i < 4; ++i) v[i] = x4[i * 256 + tid];
    float mx = 0.0f;
    #pragma unroll
    for (int i = 0; i < 4; ++i)
      mx = fmaxf(mx, fmaxf(fmaxf(fabsf(v[i].x), fabsf(v[i].y)),
                           fmaxf(fabsf(v[i].z), fabsf(v[i].w))));
    #pragma unroll
    for (int off = 32; off; off >>= 1) mx = fmaxf(mx, __shfl_xor(mx, off, 64));
    if (lane == 0) wmax[wv] = mx;
    __syncthreads();
    const float scale =
        fmaxf(fmaxf(wmax[0], wmax[1]), fmaxf(wmax[2], wmax[3])) / 127.0f;
    if (tid == 0) xs[row] = __float2half(scale);
    uint32_t* q = (uint32_t*)(xq + base);
    #pragma unroll
    for (int i = 0; i < 4; ++i) {
      float f[4] = {v[i].x, v[i].y, v[i].z, v[i].w};
      uint32_t p = 0;
      #pragma unroll
      for (int j = 0; j < 4; ++j) {
        float r = fminf(127.0f, fmaxf(-128.0f, rintf(f[j] / scale)));
        p |= ((uint32_t)((int)r & 255)) << (8 * j);
      }
      q[i * 256 + tid] = p;
    }
    return;
  }

  // generic two-pass fallback
  float mx = 0.0f;
  if (xf32) {
    const float* x = (const float*)xin + base;
    for (int k = tid * 4; k < K; k += 256 * 4) {
      float4 v = *(const float4*)(x + k);
      mx = fmaxf(mx, fmaxf(fmaxf(fabsf(v.x), fabsf(v.y)),
                           fmaxf(fabsf(v.z), fabsf(v.w))));
    }
  } else {
    const __half* x = (const __half*)xin + base;
    for (int k = tid * 8; k < K; k += 256 * 8) {
      uint4 u = *(const uint4*)(x + k);
      const __half* hp = (const __half*)&u;
      #pragma unroll
      for (int j = 0; j < 8; ++j) mx = fmaxf(mx, fabsf(__half2float(hp[j])));
    }
  }
  #pragma unroll
  for (int off = 32; off; off >>= 1) mx = fmaxf(mx, __shfl_xor(mx, off, 64));
  if (lane == 0) wmax[wv] = mx;
  __syncthreads();
  const float scale =
      fmaxf(fmaxf(wmax[0], wmax[1]), fmaxf(wmax[2], wmax[3])) / 127.0f;
  if (tid == 0) xs[row] = __float2half(scale);

  for (int k = tid * 8; k < K; k += 256 * 8) {
    float f[8];
    if (xf32) {
      const float* x = (const float*)xin + base;
      float4 a = *(const float4*)(x + k);
      float4 b = *(const float4*)(x + k + 4);
      f[0]=a.x; f[1]=a.y; f[2]=a.z; f[3]=a.w; f[4]=b.x; f[5]=b.y; f[6]=b.z; f[7]=b.w;
    } else {
      const __half* x = (const __half*)xin + base;
      uint4 u = *(const uint4*)(x + k);
      const __half* hp = (const __half*)&u;
      #pragma unroll
      for (int j = 0; j < 8; ++j) f[j] = __half2float(hp[j]);
    }
    uint32_t p0 = 0, p1 = 0;
    #pragma unroll
    for (int j = 0; j < 4; ++j) {
      float r = fminf(127.0f, fmaxf(-128.0f, rintf(f[j] / scale)));
      p0 |= ((uint32_t)((int)r & 255)) << (8 * j);
    }
    #pragma unroll
    for (int j = 0; j < 4; ++j) {
      float r = fminf(127.0f, fmaxf(-128.0f, rintf(f[4 + j] / scale)));
      p1 |= ((uint32_t)((int)r & 255)) << (8 * j);
    }
    uint2 st; st.x = p0; st.y = p1;
    *(uint2*)(xq + base + k) = st;
  }
}

// ---------------------------------------------------------------------------
// int8 GEMM, 256x256 tile, BK=128, 8 waves (2Mx4N), double-buffered LDS
// (128KiB), ONE barrier per K-tile (2614 MFMA-cyc), register-pipelined
// fragments with counted lgkmcnt, counted vmcnt (stage issued early, drained
// at tile end after ~2000 cyc in flight). Swizzle: chunk ^= (row&7) over 8
// 16B-chunks per 128B row. Requires K % 128 == 0, K/128 >= 2, M,N % 256 == 0.
// ---------------------------------------------------------------------------
__global__ __launch_bounds__(512, 2) void gemm_w8a8(
    const int8_t* __restrict__ xq, const int8_t* __restrict__ wq,
    const __half* __restrict__ xs, const float* __restrict__ wscale,
    const float* __restrict__ mos, float* __restrict__ out,
    int M, int N, int K)
{
  __shared__ int8_t sA[2][256 * 128];   // 64 KiB
  __shared__ int8_t sB[2][256 * 128];   // 64 KiB

  const int tid  = threadIdx.x;
  const int lane = tid & 63;
  const int w    = tid >> 6;
  const int wr   = w >> 2;        // 0..1 -> 128 rows of C
  const int wc   = w & 3;         // 0..3 -> 64 cols of C
  const int lr   = lane & 15;
  const int lk   = lane >> 4;

  // XCD-aware swizzle (bijective: gridDim.x % 8 == 0 for our shapes)
  int L = blockIdx.x;
  const int nwg = gridDim.x;
  if ((nwg & 7) == 0) L = (L & 7) * (nwg >> 3) + (L >> 3);
  const int ntn = N >> 8;
  const int bn = (L % ntn) << 8;
  const int bm = (L / ntn) << 8;

  v4i acc[8][4];
  #pragma unroll
  for (int i = 0; i < 8; ++i)
    #pragma unroll
    for (int j = 0; j < 4; ++j) {
      v4i z = {0, 0, 0, 0};
      acc[i][j] = z;
    }

  // stage 256x128B tile; LDS slot (r,p) holds global chunk p ^ (r&7)
  auto stageA = [&](int kt, int buf) {
    const int k0 = kt << 7;
    #pragma unroll
    for (int i = 0; i < 4; ++i) {
      const int li = i * 512 + tid;
      const int r  = li >> 3;
      const int p  = li & 7;
      const int sc = p ^ (r & 7);
      GLOAD_LDS16(xq + (size_t)(bm + r) * K + k0 + (sc << 4),
                  &sA[buf][(i * 512 + (w << 6)) << 4]);
    }
  };
  auto stageB = [&](int kt, int buf) {
    const int k0 = kt << 7;
    #pragma unroll
    for (int i = 0; i < 4; ++i) {
      const int li = i * 512 + tid;
      const int r  = li >> 3;
      const int p  = li & 7;
      const int sc = p ^ (r & 7);
      GLOAD_LDS16(wq + (size_t)(bn + r) * K + k0 + (sc << 4),
                  &sB[buf][(i * 512 + (w << 6)) << 4]);
    }
  };

  // swizzled ds_read byte offsets (kk=0); kk=1 base = kk=0 base XOR 64.
  // row&7 == lr&7 for all fragment rows (row-base offsets are x16).
  const int rowA0 = (wr << 7) + lr;
  const int aoff0 = rowA0 * 128 + ((lk ^ (lr & 7)) << 4);
  const int aoff1 = aoff0 ^ 64;
  const int rowB0 = (wc << 6) + lr;
  const int boff0 = rowB0 * 128 + ((lk ^ (lr & 7)) << 4);
  const int boff1 = boff0 ^ 64;

  const int nt = K >> 7;   // 32 for K=4096

  // prologue
  stageA(0, 0); stageB(0, 0);
  asm volatile("s_waitcnt vmcnt(0)" ::: "memory");
  __builtin_amdgcn_s_barrier();

  #pragma unroll 1
  for (int t = 0; t < nt; ++t) {
    const int buf = t & 1;
    const int8_t* Ab = sA[buf];
    const int8_t* Bb = sB[buf];
    const bool do_stage = (t + 1 < nt);
    v4i a00[4], a10[4], a01[4], a11[4], b0[4], b1[4];

    // gate burst: kk=0 h0 A-frags + kk=0 B-frags (8 reads)
    #pragma unroll
    for (int j = 0; j < 4; ++j) a00[j] = *(const v4i*)(Ab + aoff0 + j * 2048);
    #pragma unroll
    for (int j = 0; j < 4; ++j) b0[j]  = *(const v4i*)(Bb + boff0 + j * 2048);

    if (do_stage) stageA(t + 1, buf ^ 1);        // 4 gloads, ~2400cyc early

    asm volatile("s_waitcnt lgkmcnt(0)" ::: "memory");
    __builtin_amdgcn_s_setprio(1);
    #pragma unroll
    for (int j = 0; j < 4; ++j)
      #pragma unroll
      for (int ni = 0; ni < 4; ++ni)
        acc[j][ni] = __builtin_amdgcn_mfma_i32_16x16x64_i8(
            a00[j], b0[ni], acc[j][ni], 0, 0, 0);
    __builtin_amdgcn_s_setprio(0);

    // under-cover burst: h1/k0 A, k1 B, h0/k1 A (12 reads, in this order)
    #pragma unroll
    for (int j = 0; j < 4; ++j) a10[j] = *(const v4i*)(Ab + aoff0 + 8192 + j * 2048);
    #pragma unroll
    for (int j = 0; j < 4; ++j) b1[j]  = *(const v4i*)(Bb + boff1 + j * 2048);
    #pragma unroll
    for (int j = 0; j < 4; ++j) a01[j] = *(const v4i*)(Ab + aoff1 + j * 2048);

    if (do_stage) stageB(t + 1, buf ^ 1);        // 4 gloads, ~1800cyc early

    asm volatile("s_waitcnt lgkmcnt(8)" ::: "memory");   // a10 landed
    __builtin_amdgcn_s_setprio(1);
    #pragma unroll
    for (int j = 0; j < 4; ++j)
      #pragma unroll
      for (int ni = 0; ni < 4; ++ni)
        acc[4 + j][ni] = __builtin_amdgcn_mfma_i32_16x16x64_i8(
            a10[j], b0[ni], acc[4 + j][ni], 0, 0, 0);
    __builtin_amdgcn_s_setprio(0);

    // last A burst (4 reads)
    #pragma unroll
    for (int j = 0; j < 4; ++j) a11[j] = *(const v4i*)(Ab + aoff1 + 8192 + j * 2048);

    asm volatile("s_waitcnt lgkmcnt(4)" ::: "memory");   // b1,a01 landed
    __builtin_amdgcn_s_setprio(1);
    #pragma unroll
    for (int j = 0; j < 4; ++j)
      #pragma unroll
      for (int ni = 0; ni < 4; ++ni)
        acc[j][ni] = __builtin_amdgcn_mfma_i32_16x16x64_i8(
            a01[j], b1[ni], acc[j][ni], 0, 0, 0);
    __builtin_amdgcn_s_setprio(0);

    asm volatile("s_waitcnt lgkmcnt(0)" ::: "memory");   // a11 landed
    __builtin_amdgcn_s_setprio(1);
    #pragma unroll
    for (int j = 0; j < 4; ++j)
      #pragma unroll
      for (int ni = 0; ni < 4; ++ni)
        acc[4 + j][ni] = __builtin_amdgcn_mfma_i32_16x16x64_i8(
            a11[j], b1[ni], acc[4 + j][ni], 0, 0, 0);
    __builtin_amdgcn_s_setprio(0);

    // stage(t+1) must be fully resident before next iter's reads
    asm volatile("s_waitcnt vmcnt(0)" ::: "memory");
    __builtin_amdgcn_s_barrier();
  }

  // epilogue: out = (float(half(acc*s_out)) * wscale[n]) * float(half_scale[m])
  const float s_out = mos[0];
  #pragma unroll
  for (int ni = 0; ni < 4; ++ni) {
    const int n_g = bn + (wc << 6) + ni * 16 + lr;
    const float wsc = wscale[n_g];
    #pragma unroll
    for (int mi = 0; mi < 8; ++mi) {
      #pragma unroll
      for (int j = 0; j < 4; ++j) {
        const int m_g = bm + (wr << 7) + mi * 16 + lk * 4 + j;
        const float y = __half2float(__float2half((float)acc[mi][ni][j] * s_out));
        out[(size_t)m_g * N + n_g] = (y * wsc) * __half2float(xs[m_g]);
      }
    }
  }
}

// ---------------------------------------------------------------------------
extern "C" void kernel_launch(void* const* d_in, const int* in_sizes, int n_in,
                              void* d_out, int out_size, void* d_ws, size_t ws_size,
                              hipStream_t stream) {
  const void*  x      = d_in[0];
  const void*  win    = d_in[1];
  const float* wscale = (const float*)d_in[2];
  const float* mos    = (const float*)d_in[3];
  float*       out    = (float*)d_out;

  const int N = in_sizes[2];            // 4096
  const int K = in_sizes[1] / N;        // 4096
  const int M = in_sizes[0] / K;        // 8192

  int8_t* xq = (int8_t*)d_ws + XQ_OFF;
  __half* xs = (__half*)((char*)d_ws + XS_OFF);
  int8_t* w8 = (int8_t*)d_ws + W8_OFF;

  repack_w<<<2048, 256, 0, stream>>>(win, w8, N * K);
  quant_rows<<<M, 256, 0, stream>>>(x, xq, xs, K);

  gemm_w8a8<<<dim3((M >> 8) * (N >> 8)), 512, 0, stream>>>(
      xq, w8, xs, wscale, mos, out, M, N, K);
}